// Round 12
// baseline (180.101 us; speedup 1.0000x reference)
//
#include <hip/hip_runtime.h>
#include <hip/hip_bf16.h>

#define TT 512
#define BB 64
#define HH 512
#define KK 16

#define NCH 16            // scan chunks per batch (measured optimum: r5 vs r9)
#define CST (TT / NCH)    // steps per chunk = 32

typedef __attribute__((ext_vector_type(8))) short bf16x8;
typedef __attribute__((ext_vector_type(4))) short bf16x4;
typedef __attribute__((ext_vector_type(4))) float f32x4;

// v_mfma_f32_16x16x16_bf16 — legacy gfx90a spelling, carried forward on gfx950.
// NOTE: do NOT gate on __has_builtin (false in the host pass); call directly.
#define MFMA_K16(A, B, C) __builtin_amdgcn_mfma_f32_16x16x16bf16_1k(A, B, C, 0, 0, 0)

__device__ __forceinline__ unsigned short f2bf(float f) {
    union { __hip_bfloat16 h; unsigned short u; } cvt;
    cvt.h = __float2bfloat16(f);
    return cvt.u;
}

// branch-free RNE f32->bf16 (inputs are finite non-NaN here)
__device__ __forceinline__ short rne_bf(float x) {
    unsigned u = __float_as_uint(x);
    u += 0x7fffu + ((u >> 16) & 1u);
    return (short)(u >> 16);
}

__device__ __forceinline__ float bf2f(short s) {
    return __uint_as_float(((unsigned)(unsigned short)s) << 16);
}

// ---------------------------------------------------------------------------
// prep: W1 -> W1t (bf16 [n][k]); W2 -> W2t (bf16 [n][k]); zero out[0] + cnt.
// ---------------------------------------------------------------------------
__global__ void prep_kernel(const float* __restrict__ W1, const float* __restrict__ W2,
                            unsigned short* __restrict__ W1t, unsigned short* __restrict__ W2t,
                            int* __restrict__ cnt, float* __restrict__ out) {
    const int bi = blockIdx.x, tx = threadIdx.x;
    if (bi < 64) {
        __shared__ float Ls[64][65];
        const int ti = bi & 7, tj = bi >> 3;
        const int r0 = ti * 64, c0 = tj * 64;
        const int r = tx >> 4, c4 = (tx & 15) * 4;
#pragma unroll
        for (int i = 0; i < 4; ++i) {
            float4 v = *(const float4*)(W1 + (size_t)(r0 + r + 16 * i) * HH + c0 + c4);
            Ls[c4 + 0][r + 16 * i] = v.x;
            Ls[c4 + 1][r + 16 * i] = v.y;
            Ls[c4 + 2][r + 16 * i] = v.z;
            Ls[c4 + 3][r + 16 * i] = v.w;
        }
        __syncthreads();
        const int rn = tx >> 4, k4 = (tx & 15) * 4;
#pragma unroll
        for (int i = 0; i < 4; ++i) {
            const int n = rn + 16 * i;
            ushort4 o;
            o.x = f2bf(Ls[n][k4 + 0]);
            o.y = f2bf(Ls[n][k4 + 1]);
            o.z = f2bf(Ls[n][k4 + 2]);
            o.w = f2bf(Ls[n][k4 + 3]);
            *(ushort4*)(W1t + (size_t)(c0 + n) * HH + r0 + k4) = o;
        }
    } else {
        if (tx == 0) out[0] = 0.0f;
        if (tx < 64) cnt[tx] = 0;
        for (int idx = tx; idx < 16 * HH; idx += 256) {
            const int n = idx >> 9, k = idx & 511;
            W2t[idx] = f2bf(W2[k * KK + n]);
        }
    }
}

// ---------------------------------------------------------------------------
// em = relu(hidden @ W1 + b1) @ W2 + b2, bf16 MFMA both GEMMs, fp32 accum.
// v9 = round-0 kernel verbatim (best measured em across 11 variants).
// ---------------------------------------------------------------------------
__global__ __launch_bounds__(256, 2)
void em_kernel(const float* __restrict__ hidden, const unsigned short* __restrict__ W1t,
               const float* __restrict__ b1, const unsigned short* __restrict__ W2t,
               const float* __restrict__ b2, float* __restrict__ em) {
    __shared__ unsigned short W2ts[16 * 520];
    __shared__ __align__(16) unsigned char stage[37888];
    unsigned short* As = (unsigned short*)stage;            // [64][40] bf16
    unsigned short* Bs = (unsigned short*)(stage + 5120);   // [512][32] bf16, k-swizzled
    unsigned short* Hb = (unsigned short*)stage;            // [64][264] bf16

    const int tx = threadIdx.x;
    const int w = tx >> 6, lane = tx & 63;
    const int q = lane >> 4, nl = lane & 15;
    const int wm = w >> 1, wn = w & 1;
    const int row0 = blockIdx.x * 64;

    for (int i = tx; i < 16 * 64; i += 256) {
        const int n = i >> 6, kc = i & 63;
        *(bf16x8*)(W2ts + n * 520 + kc * 8) = *(const bf16x8*)(W2t + n * HH + kc * 8);
    }

    f32x4 acc[2][16];
#pragma unroll
    for (int mt = 0; mt < 2; ++mt)
#pragma unroll
        for (int nt = 0; nt < 16; ++nt) acc[mt][nt] = (f32x4){0.f, 0.f, 0.f, 0.f};

    for (int kt = 0; kt < 16; ++kt) {
        const int k0 = kt * 32;
        __syncthreads();
        {
            const int r = tx >> 2, c8 = (tx & 3) * 8;
            const float* src = hidden + (size_t)(row0 + r) * HH + k0 + c8;
            float4 v0 = *(const float4*)(src);
            float4 v1 = *(const float4*)(src + 4);
            bf16x8 o;
            o[0] = (short)f2bf(v0.x); o[1] = (short)f2bf(v0.y);
            o[2] = (short)f2bf(v0.z); o[3] = (short)f2bf(v0.w);
            o[4] = (short)f2bf(v1.x); o[5] = (short)f2bf(v1.y);
            o[6] = (short)f2bf(v1.z); o[7] = (short)f2bf(v1.w);
            *(bf16x8*)(As + r * 40 + c8) = o;
        }
#pragma unroll
        for (int it = 0; it < 8; ++it) {
            const int c = it * 256 + tx;
            const int n = c >> 2, slot = c & 3;
            const int kc = slot ^ ((n >> 1) & 3);
            __builtin_amdgcn_global_load_lds(
                (const __attribute__((address_space(1))) void*)(W1t + (size_t)n * HH + k0 + kc * 8),
                (__attribute__((address_space(3))) void*)(Bs + c * 8),
                16, 0, 0);
        }
        __syncthreads();
        bf16x8 af[2];
#pragma unroll
        for (int mt = 0; mt < 2; ++mt)
            af[mt] = *(const bf16x8*)(As + (32 * wm + 16 * mt + nl) * 40 + q * 8);
#pragma unroll
        for (int nt = 0; nt < 16; ++nt) {
            const int n = 256 * wn + 16 * nt + nl;
            const int slot = q ^ ((n >> 1) & 3);
            bf16x8 bf = *(const bf16x8*)(Bs + n * 32 + slot * 8);
            acc[0][nt] = __builtin_amdgcn_mfma_f32_16x16x32_bf16(af[0], bf, acc[0][nt], 0, 0, 0);
            acc[1][nt] = __builtin_amdgcn_mfma_f32_16x16x32_bf16(af[1], bf, acc[1][nt], 0, 0, 0);
        }
    }

    f32x4 acc2 = (f32x4){0.f, 0.f, 0.f, 0.f};
    for (int c = 0; c < 2; ++c) {
        __syncthreads();
        if (wn == c) {
#pragma unroll
            for (int nt = 0; nt < 16; ++nt) {
                const float bv = b1[c * 256 + 16 * nt + nl];
#pragma unroll
                for (int mt = 0; mt < 2; ++mt) {
#pragma unroll
                    for (int r = 0; r < 4; ++r) {
                        float v = acc[mt][nt][r] + bv;
                        v = v > 0.f ? v : 0.f;
                        const int row = 32 * wm + 16 * mt + q * 4 + r;
                        Hb[row * 264 + nt * 16 + nl] = f2bf(v);
                    }
                }
            }
        }
        __syncthreads();
#pragma unroll
        for (int ks = 0; ks < 8; ++ks) {
            bf16x8 a2 = *(const bf16x8*)(Hb + (16 * w + nl) * 264 + ks * 32 + q * 8);
            bf16x8 b2f = *(const bf16x8*)(W2ts + nl * 520 + c * 256 + ks * 32 + q * 8);
            acc2 = __builtin_amdgcn_mfma_f32_16x16x32_bf16(a2, b2f, acc2, 0, 0, 0);
        }
    }
#pragma unroll
    for (int r = 0; r < 4; ++r) {
        const int row = row0 + 16 * w + q * 4 + r;
        em[(size_t)row * KK + nl] = acc2[r] + b2[nl];
    }
}

// ---------------------------------------------------------------------------
// Merged scan (Phase A) + gold + FUSED combine (last-block reduction).
// Blocks [0,256): scan — 16 chunks x 32 steps per batch; batch b's 16 chunks
// live in blocks 4b..4b+3. After a block's 4 waves commit their P-products,
// threadfence + per-batch arrival counter; the LAST of the 4 blocks runs the
// combine for batch b inline (wave 0; 4 redundant 16-lane groups; lane 0
// commits). Deadlock-free (no spinning). Blocks [256,384): gold gather-sum.
// Combine math/order identical to the standalone kernel -> bit-identical out.
// ---------------------------------------------------------------------------
__global__ void scan_gold_kernel(const float* __restrict__ em, const float* __restrict__ trans,
                                 const int* __restrict__ lens, const int* __restrict__ tags,
                                 float* __restrict__ Pfull, float* __restrict__ Cfull,
                                 float* __restrict__ Ppart, float* __restrict__ Cpart,
                                 int* __restrict__ cnt, float* __restrict__ out) {
    __shared__ float trs[256];
    __shared__ float red[4];
    __shared__ int arrival;
    const int tx = threadIdx.x;

    if (blockIdx.x >= 256) {
        // ---- gold: parallel gather-sum, thread=(t,b), b innermost ----
        trs[tx] = __logf(bf2f(rne_bf(__expf(trans[tx]))));
        __syncthreads();
        const int idx = (blockIdx.x - 256) * 256 + tx;
        const int t = idx >> 6, b = idx & 63;
        const int L = lens[b];
        float v = 0.0f;
        if (t < L) {
            const int tg = tags[t * BB + b];
            v = em[((size_t)t * BB + b) * KK + tg];
            if (t > 0) v += trs[tg * 16 + tags[(t - 1) * BB + b]];
        }
#pragma unroll
        for (int dd = 1; dd < 64; dd <<= 1) v += __shfl_xor(v, dd, 64);
        if ((tx & 63) == 0) red[tx >> 6] = v;
        __syncthreads();
        if (tx == 0) atomicAdd(out, -(red[0] + red[1] + red[2] + red[3]));
        return;
    }

    // ---- scan ----
    const int id = blockIdx.x * 4 + (tx >> 6);   // 0..1023
    const int lane = tx & 63, q = lane >> 4, col = lane & 15;
    const int b = id >> 4, c = id & 15;          // b constant per block (= blockIdx>>2)

    // A-row factors: lane holds row m=col of M: mf[i] = bf16(exp(T[col][4q+i]))
    float mf[4];
    {
        float4 tv = *(const float4*)(trans + col * 16 + 4 * q);
        mf[0] = bf2f(rne_bf(__expf(tv.x)));
        mf[1] = bf2f(rne_bf(__expf(tv.y)));
        mf[2] = bf2f(rne_bf(__expf(tv.z)));
        mf[3] = bf2f(rne_bf(__expf(tv.w)));
    }
    const int Lm1 = lens[b] - 1;
    const int tb0 = CST * c;

    // prefetch ring: raw em values, load->use distance 8 steps
    float ebuf[8];
#pragma unroll
    for (int i = 0; i < 8; ++i)
        ebuf[i] = em[(size_t)((tb0 + i) * BB + b) * KK + col];

    // B-frag = identity: B[k=4q+i][n=col]
    bf16x4 gb;
#pragma unroll
    for (int i = 0; i < 4; ++i)
        gb[i] = (4 * q + i == col) ? rne_bf(1.0f) : (short)0;

    const f32x4 zc = (f32x4){0.f, 0.f, 0.f, 0.f};
    f32x4 d = (f32x4){0.f, 0.f, 0.f, 0.f};
    float K = 1.0f, rk = 1.0f, lk = 0.0f, Cacc = 0.0f;

    for (int sb = 0; sb < CST; sb += 8) {
        const bool refill = (sb < CST - 8);
#pragma unroll
        for (int s8 = 0; s8 < 8; ++s8) {
            const int t = tb0 + sb + s8;
            const float eraw = ebuf[s8];
            if (refill)
                ebuf[s8] = em[(size_t)((t + 8) * BB + b) * KK + col];
            float ev = __expf(eraw);
            if ((s8 & 3) == 0 && (sb + s8) >= 4) {  // lagged renorm (off-chain)
                ev *= rk;
                Cacc += lk;
            }
            bf16x4 af;
            af[0] = rne_bf(ev * mf[0]); af[1] = rne_bf(ev * mf[1]);
            af[2] = rne_bf(ev * mf[2]); af[3] = rne_bf(ev * mf[3]);
            if (s8 == 0) {
                if (sb == 0 && c == 0) {  // t=0: A_0 = diag(exp(e_0))
#pragma unroll
                    for (int i = 0; i < 4; ++i)
                        af[i] = (4 * q + i == col) ? rne_bf(ev) : (short)0;
                }
            }
            d = MFMA_K16(af, gb, zc);
            if ((s8 & 3) == 1) {  // lagged capture of P[0][0]
                K = __shfl(d[0], 0, 64);
                const float Km = fmaxf(K, 1e-30f);
                rk = 1.0f / Km;
                lk = __logf(Km);
            }
            if (t == Lm1) {  // save partial product (fp32) + its scale
#pragma unroll
                for (int r = 0; r < 4; ++r)
                    Ppart[b * 256 + (4 * q + r) * 16 + col] = d[r];
                if (lane == 0) Cpart[b] = Cacc;
            }
            gb[0] = rne_bf(d[0]); gb[1] = rne_bf(d[1]);
            gb[2] = rne_bf(d[2]); gb[3] = rne_bf(d[3]);
        }
    }
#pragma unroll
    for (int r = 0; r < 4; ++r)
        Pfull[(size_t)(b * NCH + c) * 256 + (4 * q + r) * 16 + col] = d[r];
    if (lane == 0) Cfull[b * NCH + c] = Cacc;

    // ---- last-block combine (threadFenceReduction pattern) ----
    __threadfence();                 // release: make this block's P/C visible
    __syncthreads();
    if (tx == 0) arrival = atomicAdd(&cnt[b], 1);
    __syncthreads();
    if (arrival != 3) return;        // not the last of batch b's 4 blocks
    __threadfence();                 // acquire: other blocks' P/C now visible
    if (tx >= 64) return;            // wave 0 only

    // combine for batch b: 4 redundant 16-lane groups (shfl stays in-group)
    const int grp = tx >> 4, j = tx & 15;
    const int base = grp << 4;
    const int cstar = (lens[b] - 1) / CST;

    float g = 1.0f, acc = 0.0f;
    for (int cc = 0; cc < NCH; ++cc) {
        const bool act = (cc <= cstar);
        const float* P = (cc < cstar) ? (Pfull + (size_t)(b * NCH + cc) * 256)
                                      : (Ppart + b * 256);
        float gn = 0.0f;
#pragma unroll
        for (int k = 0; k < 16; ++k) {
            const float gk = __shfl(g, base + k, 64);
            gn += P[j * 16 + k] * gk;
        }
        if (act) {
            float m = gn;
#pragma unroll
            for (int dd = 1; dd < 16; dd <<= 1) m = fmaxf(m, __shfl_xor(m, dd, 64));
            g = gn / m;
            acc += __logf(m) + ((cc < cstar) ? Cfull[b * NCH + cc] : Cpart[b]);
        }
    }
    float ssum = g;
#pragma unroll
    for (int dd = 1; dd < 16; dd <<= 1) ssum += __shfl_xor(ssum, dd, 64);
    const float fwd = acc + __logf(ssum);
    if (tx == 0) atomicAdd(out, fwd);
}

extern "C" void kernel_launch(void* const* d_in, const int* in_sizes, int n_in,
                              void* d_out, int out_size, void* d_ws, size_t ws_size,
                              hipStream_t stream) {
    const float* hidden = (const float*)d_in[0];
    const float* W1     = (const float*)d_in[1];
    const float* b1     = (const float*)d_in[2];
    const float* W2     = (const float*)d_in[3];
    const float* b2     = (const float*)d_in[4];
    const float* trans  = (const float*)d_in[5];
    const int*   lens   = (const int*)d_in[6];
    const int*   tags   = (const int*)d_in[7];
    float* out = (float*)d_out;

    char* ws = (char*)d_ws;
    float* em = (float*)ws;                                   // 2 MB
    unsigned short* W1t = (unsigned short*)(ws + 2097152);    // 512 KB
    unsigned short* W2t = (unsigned short*)(ws + 2621440);    // 16 KB
    float* Pfull = (float*)(ws + 2637824);                    // 1 MB (64*16*256*4)
    float* Cfull = (float*)(ws + 3686400);                    // 4 KB
    float* Ppart = (float*)(ws + 3690496);                    // 64 KB
    float* Cpart = (float*)(ws + 3756032);                    // 256 B
    int*   cnt   = (int*)(ws + 3756288);                      // 256 B

    prep_kernel<<<65, 256, 0, stream>>>(W1, W2, W1t, W2t, cnt, out);
    em_kernel<<<512, 256, 0, stream>>>(hidden, W1t, b1, W2t, b2, em);
    scan_gold_kernel<<<384, 256, 0, stream>>>(em, trans, lens, tags,
                                              Pfull, Cfull, Ppart, Cpart, cnt, out);
}

// Round 13
// 149.627 us; speedup vs baseline: 1.2037x; 1.2037x over previous
//
#include <hip/hip_runtime.h>
#include <hip/hip_bf16.h>

#define TT 512
#define BB 64
#define HH 512
#define KK 16

#define NCH 16            // scan chunks per batch (measured optimum: r5 vs r9)
#define CST (TT / NCH)    // steps per chunk = 32

typedef __attribute__((ext_vector_type(8))) short bf16x8;
typedef __attribute__((ext_vector_type(4))) short bf16x4;
typedef __attribute__((ext_vector_type(4))) float f32x4;

// v_mfma_f32_16x16x16_bf16 — legacy gfx90a spelling, carried forward on gfx950.
// NOTE: do NOT gate on __has_builtin (false in the host pass); call directly.
#define MFMA_K16(A, B, C) __builtin_amdgcn_mfma_f32_16x16x16bf16_1k(A, B, C, 0, 0, 0)

__device__ __forceinline__ unsigned short f2bf(float f) {
    union { __hip_bfloat16 h; unsigned short u; } cvt;
    cvt.h = __float2bfloat16(f);
    return cvt.u;
}

// branch-free RNE f32->bf16 (inputs are finite non-NaN here)
__device__ __forceinline__ short rne_bf(float x) {
    unsigned u = __float_as_uint(x);
    u += 0x7fffu + ((u >> 16) & 1u);
    return (short)(u >> 16);
}

__device__ __forceinline__ float bf2f(short s) {
    return __uint_as_float(((unsigned)(unsigned short)s) << 16);
}

// ---------------------------------------------------------------------------
// prep: W1 -> W1t (bf16 [n][k]); W2 -> W2t (bf16 [n][k]); zero out[0].
// ---------------------------------------------------------------------------
__global__ void prep_kernel(const float* __restrict__ W1, const float* __restrict__ W2,
                            unsigned short* __restrict__ W1t, unsigned short* __restrict__ W2t,
                            float* __restrict__ out) {
    const int bi = blockIdx.x, tx = threadIdx.x;
    if (bi < 64) {
        __shared__ float Ls[64][65];
        const int ti = bi & 7, tj = bi >> 3;
        const int r0 = ti * 64, c0 = tj * 64;
        const int r = tx >> 4, c4 = (tx & 15) * 4;
#pragma unroll
        for (int i = 0; i < 4; ++i) {
            float4 v = *(const float4*)(W1 + (size_t)(r0 + r + 16 * i) * HH + c0 + c4);
            Ls[c4 + 0][r + 16 * i] = v.x;
            Ls[c4 + 1][r + 16 * i] = v.y;
            Ls[c4 + 2][r + 16 * i] = v.z;
            Ls[c4 + 3][r + 16 * i] = v.w;
        }
        __syncthreads();
        const int rn = tx >> 4, k4 = (tx & 15) * 4;
#pragma unroll
        for (int i = 0; i < 4; ++i) {
            const int n = rn + 16 * i;
            ushort4 o;
            o.x = f2bf(Ls[n][k4 + 0]);
            o.y = f2bf(Ls[n][k4 + 1]);
            o.z = f2bf(Ls[n][k4 + 2]);
            o.w = f2bf(Ls[n][k4 + 3]);
            *(ushort4*)(W1t + (size_t)(c0 + n) * HH + r0 + k4) = o;
        }
    } else {
        if (tx == 0) out[0] = 0.0f;
        for (int idx = tx; idx < 16 * HH; idx += 256) {
            const int n = idx >> 9, k = idx & 511;
            W2t[idx] = f2bf(W2[k * KK + n]);
        }
    }
}

// ---------------------------------------------------------------------------
// em = relu(hidden @ W1 + b1) @ W2 + b2, bf16 MFMA both GEMMs, fp32 accum.
// v9 = round-0 kernel verbatim (best measured em across 11 variants:
// 42.6-44.5 µs; all pipelining/occupancy/tile variants landed 42-58).
// ---------------------------------------------------------------------------
__global__ __launch_bounds__(256, 2)
void em_kernel(const float* __restrict__ hidden, const unsigned short* __restrict__ W1t,
               const float* __restrict__ b1, const unsigned short* __restrict__ W2t,
               const float* __restrict__ b2, float* __restrict__ em) {
    __shared__ unsigned short W2ts[16 * 520];
    __shared__ __align__(16) unsigned char stage[37888];
    unsigned short* As = (unsigned short*)stage;            // [64][40] bf16
    unsigned short* Bs = (unsigned short*)(stage + 5120);   // [512][32] bf16, k-swizzled
    unsigned short* Hb = (unsigned short*)stage;            // [64][264] bf16

    const int tx = threadIdx.x;
    const int w = tx >> 6, lane = tx & 63;
    const int q = lane >> 4, nl = lane & 15;
    const int wm = w >> 1, wn = w & 1;
    const int row0 = blockIdx.x * 64;

    for (int i = tx; i < 16 * 64; i += 256) {
        const int n = i >> 6, kc = i & 63;
        *(bf16x8*)(W2ts + n * 520 + kc * 8) = *(const bf16x8*)(W2t + n * HH + kc * 8);
    }

    f32x4 acc[2][16];
#pragma unroll
    for (int mt = 0; mt < 2; ++mt)
#pragma unroll
        for (int nt = 0; nt < 16; ++nt) acc[mt][nt] = (f32x4){0.f, 0.f, 0.f, 0.f};

    for (int kt = 0; kt < 16; ++kt) {
        const int k0 = kt * 32;
        __syncthreads();
        {
            const int r = tx >> 2, c8 = (tx & 3) * 8;
            const float* src = hidden + (size_t)(row0 + r) * HH + k0 + c8;
            float4 v0 = *(const float4*)(src);
            float4 v1 = *(const float4*)(src + 4);
            bf16x8 o;
            o[0] = (short)f2bf(v0.x); o[1] = (short)f2bf(v0.y);
            o[2] = (short)f2bf(v0.z); o[3] = (short)f2bf(v0.w);
            o[4] = (short)f2bf(v1.x); o[5] = (short)f2bf(v1.y);
            o[6] = (short)f2bf(v1.z); o[7] = (short)f2bf(v1.w);
            *(bf16x8*)(As + r * 40 + c8) = o;
        }
#pragma unroll
        for (int it = 0; it < 8; ++it) {
            const int c = it * 256 + tx;
            const int n = c >> 2, slot = c & 3;
            const int kc = slot ^ ((n >> 1) & 3);
            __builtin_amdgcn_global_load_lds(
                (const __attribute__((address_space(1))) void*)(W1t + (size_t)n * HH + k0 + kc * 8),
                (__attribute__((address_space(3))) void*)(Bs + c * 8),
                16, 0, 0);
        }
        __syncthreads();
        bf16x8 af[2];
#pragma unroll
        for (int mt = 0; mt < 2; ++mt)
            af[mt] = *(const bf16x8*)(As + (32 * wm + 16 * mt + nl) * 40 + q * 8);
#pragma unroll
        for (int nt = 0; nt < 16; ++nt) {
            const int n = 256 * wn + 16 * nt + nl;
            const int slot = q ^ ((n >> 1) & 3);
            bf16x8 bf = *(const bf16x8*)(Bs + n * 32 + slot * 8);
            acc[0][nt] = __builtin_amdgcn_mfma_f32_16x16x32_bf16(af[0], bf, acc[0][nt], 0, 0, 0);
            acc[1][nt] = __builtin_amdgcn_mfma_f32_16x16x32_bf16(af[1], bf, acc[1][nt], 0, 0, 0);
        }
    }

    f32x4 acc2 = (f32x4){0.f, 0.f, 0.f, 0.f};
    for (int c = 0; c < 2; ++c) {
        __syncthreads();
        if (wn == c) {
#pragma unroll
            for (int nt = 0; nt < 16; ++nt) {
                const float bv = b1[c * 256 + 16 * nt + nl];
#pragma unroll
                for (int mt = 0; mt < 2; ++mt) {
#pragma unroll
                    for (int r = 0; r < 4; ++r) {
                        float v = acc[mt][nt][r] + bv;
                        v = v > 0.f ? v : 0.f;
                        const int row = 32 * wm + 16 * mt + q * 4 + r;
                        Hb[row * 264 + nt * 16 + nl] = f2bf(v);
                    }
                }
            }
        }
        __syncthreads();
#pragma unroll
        for (int ks = 0; ks < 8; ++ks) {
            bf16x8 a2 = *(const bf16x8*)(Hb + (16 * w + nl) * 264 + ks * 32 + q * 8);
            bf16x8 b2f = *(const bf16x8*)(W2ts + nl * 520 + c * 256 + ks * 32 + q * 8);
            acc2 = __builtin_amdgcn_mfma_f32_16x16x32_bf16(a2, b2f, acc2, 0, 0, 0);
        }
    }
#pragma unroll
    for (int r = 0; r < 4; ++r) {
        const int row = row0 + 16 * w + q * 4 + r;
        em[(size_t)row * KK + nl] = acc2[r] + b2[nl];
    }
}

// ---------------------------------------------------------------------------
// Merged scan (Phase A) + gold — round-5 structure (NO fused combine: the
// per-block device-scope threadfence needed for in-kernel combine costs
// ~15 µs in L2 writebacks [measured r12]; the kernel boundary is cheaper).
// Blocks [0,256): chunked matrix-product scan, 16 chunks x 32 steps per
// batch (1024 waves). Blocks [256,384): gold gather-sum.
// Scan: wave computes P_c = prod_{t in chunk} A_t, A_t = diag(exp(e_t))*M,
// M = bf16(exp(T)); chunk 0 absorbs t=0 as diag(exp(e_0)). Feedback via
// in-lane rne+pack (D-layout == B-frag layout). Renorm every 4 steps (lagged
// P[0][0] capture, folded into exp(e) off-chain). The wave whose chunk holds
// Lm1 also saves the partial product (fp32).
// ---------------------------------------------------------------------------
__global__ void scan_gold_kernel(const float* __restrict__ em, const float* __restrict__ trans,
                                 const int* __restrict__ lens, const int* __restrict__ tags,
                                 float* __restrict__ Pfull, float* __restrict__ Cfull,
                                 float* __restrict__ Ppart, float* __restrict__ Cpart,
                                 float* __restrict__ out) {
    __shared__ float trs[256];
    __shared__ float red[4];
    const int tx = threadIdx.x;

    if (blockIdx.x >= 256) {
        // ---- gold: parallel gather-sum, thread=(t,b), b innermost ----
        trs[tx] = __logf(bf2f(rne_bf(__expf(trans[tx]))));
        __syncthreads();
        const int idx = (blockIdx.x - 256) * 256 + tx;
        const int t = idx >> 6, b = idx & 63;
        const int L = lens[b];
        float v = 0.0f;
        if (t < L) {
            const int tg = tags[t * BB + b];
            v = em[((size_t)t * BB + b) * KK + tg];
            if (t > 0) v += trs[tg * 16 + tags[(t - 1) * BB + b]];
        }
#pragma unroll
        for (int dd = 1; dd < 64; dd <<= 1) v += __shfl_xor(v, dd, 64);
        if ((tx & 63) == 0) red[tx >> 6] = v;
        __syncthreads();
        if (tx == 0) atomicAdd(out, -(red[0] + red[1] + red[2] + red[3]));
        return;
    }

    // ---- scan ----
    const int id = blockIdx.x * 4 + (tx >> 6);   // 0..1023
    const int lane = tx & 63, q = lane >> 4, col = lane & 15;
    const int b = id >> 4, c = id & 15;

    // A-row factors: lane holds row m=col of M: mf[i] = bf16(exp(T[col][4q+i]))
    float mf[4];
    {
        float4 tv = *(const float4*)(trans + col * 16 + 4 * q);
        mf[0] = bf2f(rne_bf(__expf(tv.x)));
        mf[1] = bf2f(rne_bf(__expf(tv.y)));
        mf[2] = bf2f(rne_bf(__expf(tv.z)));
        mf[3] = bf2f(rne_bf(__expf(tv.w)));
    }
    const int Lm1 = lens[b] - 1;
    const int tb0 = CST * c;

    // prefetch ring: raw em values, load->use distance 8 steps
    float ebuf[8];
#pragma unroll
    for (int i = 0; i < 8; ++i)
        ebuf[i] = em[(size_t)((tb0 + i) * BB + b) * KK + col];

    // B-frag = identity: B[k=4q+i][n=col]
    bf16x4 gb;
#pragma unroll
    for (int i = 0; i < 4; ++i)
        gb[i] = (4 * q + i == col) ? rne_bf(1.0f) : (short)0;

    const f32x4 zc = (f32x4){0.f, 0.f, 0.f, 0.f};
    f32x4 d = (f32x4){0.f, 0.f, 0.f, 0.f};
    float K = 1.0f, rk = 1.0f, lk = 0.0f, Cacc = 0.0f;

    for (int sb = 0; sb < CST; sb += 8) {
        const bool refill = (sb < CST - 8);
#pragma unroll
        for (int s8 = 0; s8 < 8; ++s8) {
            const int t = tb0 + sb + s8;
            const float eraw = ebuf[s8];
            if (refill)
                ebuf[s8] = em[(size_t)((t + 8) * BB + b) * KK + col];
            float ev = __expf(eraw);
            if ((s8 & 3) == 0 && (sb + s8) >= 4) {  // lagged renorm (off-chain)
                ev *= rk;
                Cacc += lk;
            }
            bf16x4 af;
            af[0] = rne_bf(ev * mf[0]); af[1] = rne_bf(ev * mf[1]);
            af[2] = rne_bf(ev * mf[2]); af[3] = rne_bf(ev * mf[3]);
            if (s8 == 0) {
                if (sb == 0 && c == 0) {  // t=0: A_0 = diag(exp(e_0))
#pragma unroll
                    for (int i = 0; i < 4; ++i)
                        af[i] = (4 * q + i == col) ? rne_bf(ev) : (short)0;
                }
            }
            d = MFMA_K16(af, gb, zc);
            if ((s8 & 3) == 1) {  // lagged capture of P[0][0]
                K = __shfl(d[0], 0, 64);
                const float Km = fmaxf(K, 1e-30f);
                rk = 1.0f / Km;
                lk = __logf(Km);
            }
            if (t == Lm1) {  // save partial product (fp32) + its scale
#pragma unroll
                for (int r = 0; r < 4; ++r)
                    Ppart[b * 256 + (4 * q + r) * 16 + col] = d[r];
                if (lane == 0) Cpart[b] = Cacc;
            }
            gb[0] = rne_bf(d[0]); gb[1] = rne_bf(d[1]);
            gb[2] = rne_bf(d[2]); gb[3] = rne_bf(d[3]);
        }
    }
#pragma unroll
    for (int r = 0; r < 4; ++r)
        Pfull[(size_t)(b * NCH + c) * 256 + (4 * q + r) * 16 + col] = d[r];
    if (lane == 0) Cfull[b * NCH + c] = Cacc;
}

// ---------------------------------------------------------------------------
// Phase B: per batch, ones-vector through P_0..P_{c*-1}, then partial P-hat.
// fp32 matvecs, per-chunk max-normalization, final lse. 16 blocks x 64 thr.
// ---------------------------------------------------------------------------
__global__ void combine_kernel(const int* __restrict__ lens,
                               const float* __restrict__ Pfull, const float* __restrict__ Cfull,
                               const float* __restrict__ Ppart, const float* __restrict__ Cpart,
                               float* __restrict__ out) {
    const int lane = threadIdx.x;
    const int grp = lane >> 4, j = lane & 15;
    const int b = blockIdx.x * 4 + grp;
    const int base = grp << 4;
    const int cstar = (lens[b] - 1) / CST;

    float g = 1.0f, acc = 0.0f;
    for (int c = 0; c < NCH; ++c) {
        const bool act = (c <= cstar);
        const float* P = (c < cstar) ? (Pfull + (size_t)(b * NCH + c) * 256)
                                     : (Ppart + b * 256);
        float gn = 0.0f;
#pragma unroll
        for (int k = 0; k < 16; ++k) {
            const float gk = __shfl(g, base + k, 64);
            gn += P[j * 16 + k] * gk;
        }
        if (act) {
            float m = gn;
#pragma unroll
            for (int dd = 1; dd < 16; dd <<= 1) m = fmaxf(m, __shfl_xor(m, dd, 64));
            g = gn / m;
            acc += __logf(m) + ((c < cstar) ? Cfull[b * NCH + c] : Cpart[b]);
        }
    }
    float ssum = g;
#pragma unroll
    for (int dd = 1; dd < 16; dd <<= 1) ssum += __shfl_xor(ssum, dd, 64);
    const float fwd = acc + __logf(ssum);
    if (j == 0) atomicAdd(out, fwd);
}

extern "C" void kernel_launch(void* const* d_in, const int* in_sizes, int n_in,
                              void* d_out, int out_size, void* d_ws, size_t ws_size,
                              hipStream_t stream) {
    const float* hidden = (const float*)d_in[0];
    const float* W1     = (const float*)d_in[1];
    const float* b1     = (const float*)d_in[2];
    const float* W2     = (const float*)d_in[3];
    const float* b2     = (const float*)d_in[4];
    const float* trans  = (const float*)d_in[5];
    const int*   lens   = (const int*)d_in[6];
    const int*   tags   = (const int*)d_in[7];
    float* out = (float*)d_out;

    char* ws = (char*)d_ws;
    float* em = (float*)ws;                                   // 2 MB
    unsigned short* W1t = (unsigned short*)(ws + 2097152);    // 512 KB
    unsigned short* W2t = (unsigned short*)(ws + 2621440);    // 16 KB
    float* Pfull = (float*)(ws + 2637824);                    // 1 MB (64*16*256*4)
    float* Cfull = (float*)(ws + 3686400);                    // 4 KB
    float* Ppart = (float*)(ws + 3690496);                    // 64 KB
    float* Cpart = (float*)(ws + 3756032);                    // 256 B

    prep_kernel<<<65, 256, 0, stream>>>(W1, W2, W1t, W2t, out);
    em_kernel<<<512, 256, 0, stream>>>(hidden, W1t, b1, W2t, b2, em);
    scan_gold_kernel<<<384, 256, 0, stream>>>(em, trans, lens, tags,
                                              Pfull, Cfull, Ppart, Cpart, out);
    combine_kernel<<<16, 64, 0, stream>>>(lens, Pfull, Cfull, Ppart, Cpart, out);
}

// Round 14
// 145.137 us; speedup vs baseline: 1.2409x; 1.0309x over previous
//
#include <hip/hip_runtime.h>
#include <hip/hip_bf16.h>

#define TT 512
#define BB 64
#define HH 512
#define KK 16

#define NCH 16            // scan chunks per batch (measured optimum: r5 vs r9)
#define CST (TT / NCH)    // steps per chunk = 32

typedef __attribute__((ext_vector_type(8))) short bf16x8;
typedef __attribute__((ext_vector_type(4))) short bf16x4;
typedef __attribute__((ext_vector_type(4))) float f32x4;

// v_mfma_f32_16x16x16_bf16 — legacy gfx90a spelling, carried forward on gfx950.
// NOTE: do NOT gate on __has_builtin (false in the host pass); call directly.
#define MFMA_K16(A, B, C) __builtin_amdgcn_mfma_f32_16x16x16bf16_1k(A, B, C, 0, 0, 0)

__device__ __forceinline__ unsigned short f2bf(float f) {
    union { __hip_bfloat16 h; unsigned short u; } cvt;
    cvt.h = __float2bfloat16(f);
    return cvt.u;
}

// branch-free RNE f32->bf16 (inputs are finite non-NaN here)
__device__ __forceinline__ short rne_bf(float x) {
    unsigned u = __float_as_uint(x);
    u += 0x7fffu + ((u >> 16) & 1u);
    return (short)(u >> 16);
}

__device__ __forceinline__ float bf2f(short s) {
    return __uint_as_float(((unsigned)(unsigned short)s) << 16);
}

// ---------------------------------------------------------------------------
// prep: W1 -> W1t (bf16 [n][k]); W2 -> W2t (bf16 [n][k]); zero out[0].
// ---------------------------------------------------------------------------
__global__ void prep_kernel(const float* __restrict__ W1, const float* __restrict__ W2,
                            unsigned short* __restrict__ W1t, unsigned short* __restrict__ W2t,
                            float* __restrict__ out) {
    const int bi = blockIdx.x, tx = threadIdx.x;
    if (bi < 64) {
        __shared__ float Ls[64][65];
        const int ti = bi & 7, tj = bi >> 3;
        const int r0 = ti * 64, c0 = tj * 64;
        const int r = tx >> 4, c4 = (tx & 15) * 4;
#pragma unroll
        for (int i = 0; i < 4; ++i) {
            float4 v = *(const float4*)(W1 + (size_t)(r0 + r + 16 * i) * HH + c0 + c4);
            Ls[c4 + 0][r + 16 * i] = v.x;
            Ls[c4 + 1][r + 16 * i] = v.y;
            Ls[c4 + 2][r + 16 * i] = v.z;
            Ls[c4 + 3][r + 16 * i] = v.w;
        }
        __syncthreads();
        const int rn = tx >> 4, k4 = (tx & 15) * 4;
#pragma unroll
        for (int i = 0; i < 4; ++i) {
            const int n = rn + 16 * i;
            ushort4 o;
            o.x = f2bf(Ls[n][k4 + 0]);
            o.y = f2bf(Ls[n][k4 + 1]);
            o.z = f2bf(Ls[n][k4 + 2]);
            o.w = f2bf(Ls[n][k4 + 3]);
            *(ushort4*)(W1t + (size_t)(c0 + n) * HH + r0 + k4) = o;
        }
    } else {
        if (tx == 0) out[0] = 0.0f;
        for (int idx = tx; idx < 16 * HH; idx += 256) {
            const int n = idx >> 9, k = idx & 511;
            W2t[idx] = f2bf(W2[k * KK + n]);
        }
    }
}

// ---------------------------------------------------------------------------
// em = relu(hidden @ W1 + b1) @ W2 + b2, bf16 MFMA both GEMMs, fp32 accum.
// v10: BK=64 (8 K-steps, was 16) at UNCHANGED occupancy (2 blocks/CU) and
// unchanged total bytes — isolates the per-barrier-interval fixed-latency
// term that 11 same-step-count variants could not touch. LDS 74752 B:
// As [64][72] + Bs [512][64] (8-slot source-side swizzle kc = slot^(n&7);
// LDS dest linear per the global_load_lds lane rule). W2 restaged in the
// epilogue (v5b pattern). Per-output MFMA K-chain (kk ascending inside kt)
// identical to v9 in both GEMMs -> bit-identical em.
// ---------------------------------------------------------------------------
__global__ __launch_bounds__(256, 2)
void em_kernel(const float* __restrict__ hidden, const unsigned short* __restrict__ W1t,
               const float* __restrict__ b1, const unsigned short* __restrict__ W2t,
               const float* __restrict__ b2, float* __restrict__ em) {
    // K-loop arena: As [64][72] bf16 @0 (9216 B) + Bs [512][64] @9216 (65536 B)
    // epilogue:     Hb [64][264] @0 (33792 B) + W2s [16][520] @33792 (16640 B)
    __shared__ __align__(16) unsigned char stage[74752];
    unsigned short* const As = (unsigned short*)stage;
    unsigned short* const Bs = (unsigned short*)(stage + 9216);

    const int tx = threadIdx.x;
    const int w = tx >> 6, lane = tx & 63;
    const int q = lane >> 4, nl = lane & 15;
    const int wm = w >> 1, wn = w & 1;
    const int row0 = blockIdx.x * 64;

    f32x4 acc[2][16];
#pragma unroll
    for (int mt = 0; mt < 2; ++mt)
#pragma unroll
        for (int nt = 0; nt < 16; ++nt) acc[mt][nt] = (f32x4){0.f, 0.f, 0.f, 0.f};

    for (int kt = 0; kt < 8; ++kt) {
        const int k0 = kt * 64;
        __syncthreads();
        // A tile: 64x64 fp32 -> bf16 (four float4 per thread; row tx>>2, cols (tx&3)*16..+15)
        {
            const int r = tx >> 2, c16 = (tx & 3) * 16;
            const float* src = hidden + (size_t)(row0 + r) * HH + k0 + c16;
            float4 v0 = *(const float4*)(src);
            float4 v1 = *(const float4*)(src + 4);
            float4 v2 = *(const float4*)(src + 8);
            float4 v3 = *(const float4*)(src + 12);
            bf16x8 o0, o1;
            o0[0] = (short)f2bf(v0.x); o0[1] = (short)f2bf(v0.y);
            o0[2] = (short)f2bf(v0.z); o0[3] = (short)f2bf(v0.w);
            o0[4] = (short)f2bf(v1.x); o0[5] = (short)f2bf(v1.y);
            o0[6] = (short)f2bf(v1.z); o0[7] = (short)f2bf(v1.w);
            o1[0] = (short)f2bf(v2.x); o1[1] = (short)f2bf(v2.y);
            o1[2] = (short)f2bf(v2.z); o1[3] = (short)f2bf(v2.w);
            o1[4] = (short)f2bf(v3.x); o1[5] = (short)f2bf(v3.y);
            o1[6] = (short)f2bf(v3.z); o1[7] = (short)f2bf(v3.w);
            *(bf16x8*)(As + r * 72 + c16) = o0;
            *(bf16x8*)(As + r * 72 + c16 + 8) = o1;
        }
        // B tile: 512x64 bf16 via global_load_lds; source-side 8-slot swizzle,
        // LDS destination linear in thread id (wave-uniform base + lane*16).
#pragma unroll
        for (int it = 0; it < 16; ++it) {
            const int c = it * 256 + tx;
            const int n = c >> 3, slot = c & 7;
            const int kc = slot ^ (n & 7);
            __builtin_amdgcn_global_load_lds(
                (const __attribute__((address_space(1))) void*)(W1t + (size_t)n * HH + k0 + kc * 8),
                (__attribute__((address_space(3))) void*)(Bs + c * 8),
                16, 0, 0);
        }
        __syncthreads();
        // wave tile 32x256, K=64 per step: af[mt][kk]; per-acc kk ascending (= v9 K order)
        bf16x8 af[2][2];
#pragma unroll
        for (int mt = 0; mt < 2; ++mt)
#pragma unroll
            for (int kk = 0; kk < 2; ++kk)
                af[mt][kk] = *(const bf16x8*)(As + (32 * wm + 16 * mt + nl) * 72 + kk * 32 + q * 8);
#pragma unroll
        for (int nt = 0; nt < 16; ++nt) {
            const int n = 256 * wn + 16 * nt + nl;
#pragma unroll
            for (int kk = 0; kk < 2; ++kk) {
                const int slot = (4 * kk + q) ^ (n & 7);
                bf16x8 bf = *(const bf16x8*)(Bs + n * 64 + slot * 8);
                acc[0][nt] = __builtin_amdgcn_mfma_f32_16x16x32_bf16(af[0][kk], bf, acc[0][nt], 0, 0, 0);
                acc[1][nt] = __builtin_amdgcn_mfma_f32_16x16x32_bf16(af[1][kk], bf, acc[1][nt], 0, 0, 0);
            }
        }
    }

    // ---- epilogue: restage W2 into freed arena; v9 two-phase H exchange ----
    __syncthreads();
    unsigned short* const Hb  = (unsigned short*)stage;             // [64][264]
    unsigned short* const W2s = (unsigned short*)(stage + 33792);   // [16][520]
#pragma unroll
    for (int i = tx; i < 1024; i += 256) {
        const int n = i >> 6, kc = i & 63;
        *(bf16x8*)(W2s + n * 520 + kc * 8) = *(const bf16x8*)(W2t + n * HH + kc * 8);
    }

    f32x4 acc2 = (f32x4){0.f, 0.f, 0.f, 0.f};
#pragma unroll
    for (int c = 0; c < 2; ++c) {
        if (wn == c) {
#pragma unroll
            for (int nt = 0; nt < 16; ++nt) {
                const float bv = b1[c * 256 + 16 * nt + nl];
#pragma unroll
                for (int mt = 0; mt < 2; ++mt) {
#pragma unroll
                    for (int r = 0; r < 4; ++r) {
                        float v = acc[mt][nt][r] + bv;
                        v = v > 0.f ? v : 0.f;
                        const int row = 32 * wm + 16 * mt + q * 4 + r;
                        Hb[row * 264 + nt * 16 + nl] = f2bf(v);
                    }
                }
            }
        }
        __syncthreads();
        // GEMM2 partial: k in [256c, 256c+256); same K-order as v9 (c*256+ks*32+q*8)
#pragma unroll
        for (int ks = 0; ks < 8; ++ks) {
            bf16x8 a2 = *(const bf16x8*)(Hb + (16 * w + nl) * 264 + ks * 32 + q * 8);
            bf16x8 b2f = *(const bf16x8*)(W2s + nl * 520 + c * 256 + ks * 32 + q * 8);
            acc2 = __builtin_amdgcn_mfma_f32_16x16x32_bf16(a2, b2f, acc2, 0, 0, 0);
        }
        __syncthreads();
    }
#pragma unroll
    for (int r = 0; r < 4; ++r) {
        const int row = row0 + 16 * w + q * 4 + r;
        em[(size_t)row * KK + nl] = acc2[r] + b2[nl];
    }
}

// ---------------------------------------------------------------------------
// Merged scan (Phase A) + gold — round-5 structure (NO fused combine: the
// per-block device-scope threadfence needed for in-kernel combine costs
// ~15 µs in L2 writebacks [measured r12]; the kernel boundary is cheaper).
// Blocks [0,256): chunked matrix-product scan, 16 chunks x 32 steps per
// batch (1024 waves). Blocks [256,384): gold gather-sum.
// ---------------------------------------------------------------------------
__global__ void scan_gold_kernel(const float* __restrict__ em, const float* __restrict__ trans,
                                 const int* __restrict__ lens, const int* __restrict__ tags,
                                 float* __restrict__ Pfull, float* __restrict__ Cfull,
                                 float* __restrict__ Ppart, float* __restrict__ Cpart,
                                 float* __restrict__ out) {
    __shared__ float trs[256];
    __shared__ float red[4];
    const int tx = threadIdx.x;

    if (blockIdx.x >= 256) {
        // ---- gold: parallel gather-sum, thread=(t,b), b innermost ----
        trs[tx] = __logf(bf2f(rne_bf(__expf(trans[tx]))));
        __syncthreads();
        const int idx = (blockIdx.x - 256) * 256 + tx;
        const int t = idx >> 6, b = idx & 63;
        const int L = lens[b];
        float v = 0.0f;
        if (t < L) {
            const int tg = tags[t * BB + b];
            v = em[((size_t)t * BB + b) * KK + tg];
            if (t > 0) v += trs[tg * 16 + tags[(t - 1) * BB + b]];
        }
#pragma unroll
        for (int dd = 1; dd < 64; dd <<= 1) v += __shfl_xor(v, dd, 64);
        if ((tx & 63) == 0) red[tx >> 6] = v;
        __syncthreads();
        if (tx == 0) atomicAdd(out, -(red[0] + red[1] + red[2] + red[3]));
        return;
    }

    // ---- scan ----
    const int id = blockIdx.x * 4 + (tx >> 6);   // 0..1023
    const int lane = tx & 63, q = lane >> 4, col = lane & 15;
    const int b = id >> 4, c = id & 15;

    // A-row factors: lane holds row m=col of M: mf[i] = bf16(exp(T[col][4q+i]))
    float mf[4];
    {
        float4 tv = *(const float4*)(trans + col * 16 + 4 * q);
        mf[0] = bf2f(rne_bf(__expf(tv.x)));
        mf[1] = bf2f(rne_bf(__expf(tv.y)));
        mf[2] = bf2f(rne_bf(__expf(tv.z)));
        mf[3] = bf2f(rne_bf(__expf(tv.w)));
    }
    const int Lm1 = lens[b] - 1;
    const int tb0 = CST * c;

    // prefetch ring: raw em values, load->use distance 8 steps
    float ebuf[8];
#pragma unroll
    for (int i = 0; i < 8; ++i)
        ebuf[i] = em[(size_t)((tb0 + i) * BB + b) * KK + col];

    // B-frag = identity: B[k=4q+i][n=col]
    bf16x4 gb;
#pragma unroll
    for (int i = 0; i < 4; ++i)
        gb[i] = (4 * q + i == col) ? rne_bf(1.0f) : (short)0;

    const f32x4 zc = (f32x4){0.f, 0.f, 0.f, 0.f};
    f32x4 d = (f32x4){0.f, 0.f, 0.f, 0.f};
    float K = 1.0f, rk = 1.0f, lk = 0.0f, Cacc = 0.0f;

    for (int sb = 0; sb < CST; sb += 8) {
        const bool refill = (sb < CST - 8);
#pragma unroll
        for (int s8 = 0; s8 < 8; ++s8) {
            const int t = tb0 + sb + s8;
            const float eraw = ebuf[s8];
            if (refill)
                ebuf[s8] = em[(size_t)((t + 8) * BB + b) * KK + col];
            float ev = __expf(eraw);
            if ((s8 & 3) == 0 && (sb + s8) >= 4) {  // lagged renorm (off-chain)
                ev *= rk;
                Cacc += lk;
            }
            bf16x4 af;
            af[0] = rne_bf(ev * mf[0]); af[1] = rne_bf(ev * mf[1]);
            af[2] = rne_bf(ev * mf[2]); af[3] = rne_bf(ev * mf[3]);
            if (s8 == 0) {
                if (sb == 0 && c == 0) {  // t=0: A_0 = diag(exp(e_0))
#pragma unroll
                    for (int i = 0; i < 4; ++i)
                        af[i] = (4 * q + i == col) ? rne_bf(ev) : (short)0;
                }
            }
            d = MFMA_K16(af, gb, zc);
            if ((s8 & 3) == 1) {  // lagged capture of P[0][0]
                K = __shfl(d[0], 0, 64);
                const float Km = fmaxf(K, 1e-30f);
                rk = 1.0f / Km;
                lk = __logf(Km);
            }
            if (t == Lm1) {  // save partial product (fp32) + its scale
#pragma unroll
                for (int r = 0; r < 4; ++r)
                    Ppart[b * 256 + (4 * q + r) * 16 + col] = d[r];
                if (lane == 0) Cpart[b] = Cacc;
            }
            gb[0] = rne_bf(d[0]); gb[1] = rne_bf(d[1]);
            gb[2] = rne_bf(d[2]); gb[3] = rne_bf(d[3]);
        }
    }
#pragma unroll
    for (int r = 0; r < 4; ++r)
        Pfull[(size_t)(b * NCH + c) * 256 + (4 * q + r) * 16 + col] = d[r];
    if (lane == 0) Cfull[b * NCH + c] = Cacc;
}

// ---------------------------------------------------------------------------
// Phase B: per batch, ones-vector through P_0..P_{c*-1}, then partial P-hat.
// fp32 matvecs, per-chunk max-normalization, final lse. 16 blocks x 64 thr.
// ---------------------------------------------------------------------------
__global__ void combine_kernel(const int* __restrict__ lens,
                               const float* __restrict__ Pfull, const float* __restrict__ Cfull,
                               const float* __restrict__ Ppart, const float* __restrict__ Cpart,
                               float* __restrict__ out) {
    const int lane = threadIdx.x;
    const int grp = lane >> 4, j = lane & 15;
    const int b = blockIdx.x * 4 + grp;
    const int base = grp << 4;
    const int cstar = (lens[b] - 1) / CST;

    float g = 1.0f, acc = 0.0f;
    for (int c = 0; c < NCH; ++c) {
        const bool act = (c <= cstar);
        const float* P = (c < cstar) ? (Pfull + (size_t)(b * NCH + c) * 256)
                                     : (Ppart + b * 256);
        float gn = 0.0f;
#pragma unroll
        for (int k = 0; k < 16; ++k) {
            const float gk = __shfl(g, base + k, 64);
            gn += P[j * 16 + k] * gk;
        }
        if (act) {
            float m = gn;
#pragma unroll
            for (int dd = 1; dd < 16; dd <<= 1) m = fmaxf(m, __shfl_xor(m, dd, 64));
            g = gn / m;
            acc += __logf(m) + ((c < cstar) ? Cfull[b * NCH + c] : Cpart[b]);
        }
    }
    float ssum = g;
#pragma unroll
    for (int dd = 1; dd < 16; dd <<= 1) ssum += __shfl_xor(ssum, dd, 64);
    const float fwd = acc + __logf(ssum);
    if (j == 0) atomicAdd(out, fwd);
}

extern "C" void kernel_launch(void* const* d_in, const int* in_sizes, int n_in,
                              void* d_out, int out_size, void* d_ws, size_t ws_size,
                              hipStream_t stream) {
    const float* hidden = (const float*)d_in[0];
    const float* W1     = (const float*)d_in[1];
    const float* b1     = (const float*)d_in[2];
    const float* W2     = (const float*)d_in[3];
    const float* b2     = (const float*)d_in[4];
    const float* trans  = (const float*)d_in[5];
    const int*   lens   = (const int*)d_in[6];
    const int*   tags   = (const int*)d_in[7];
    float* out = (float*)d_out;

    char* ws = (char*)d_ws;
    float* em = (float*)ws;                                   // 2 MB
    unsigned short* W1t = (unsigned short*)(ws + 2097152);    // 512 KB
    unsigned short* W2t = (unsigned short*)(ws + 2621440);    // 16 KB
    float* Pfull = (float*)(ws + 2637824);                    // 1 MB (64*16*256*4)
    float* Cfull = (float*)(ws + 3686400);                    // 4 KB
    float* Ppart = (float*)(ws + 3690496);                    // 64 KB
    float* Cpart = (float*)(ws + 3756032);                    // 256 B

    prep_kernel<<<65, 256, 0, stream>>>(W1, W2, W1t, W2t, out);
    em_kernel<<<512, 256, 0, stream>>>(hidden, W1t, b1, W2t, b2, em);
    scan_gold_kernel<<<384, 256, 0, stream>>>(em, trans, lens, tags,
                                              Pfull, Cfull, Ppart, Cpart, out);
    combine_kernel<<<16, 64, 0, stream>>>(lens, Pfull, Cfull, Ppart, Cpart, out);
}